// Round 1
// baseline (651.424 us; speedup 1.0000x reference)
//
#include <hip/hip_runtime.h>
#include <hip/hip_bf16.h>
#include <math.h>

// ---------------- sizes ----------------
#define B_ 16
#define HW 262144        // 512*512
#define NB2 64
#define NB1 8
#define C1IN 9
#define C1OUT 128
#define POOL 33          // pooled spatial
#define C2OUT 1024
#define K2 1152          // 128*9
#define M_SP 1089        // 33*33

// ws layout (in floats/uints; all 4-byte elems)
#define OFF_CNT2 0                       // 16*4096 uint
#define OFF_CNT1 (OFF_CNT2 + 16*4096)    // 16*8 uint (pad)
#define OFF_HAB  (OFF_CNT1 + 512)        // 16*4096 f32 (transposed, normalized 2D hist)
#define OFF_HL   (OFF_HAB + 16*4096)     // 16*8 f32
#define OFF_FEAT (OFF_HL + 512)          // 16*1024 f32
#define OFF_W2T  (OFF_FEAT + 16*1024)    // 1152*1024 f32
#define OFF_Z    (OFF_W2T + 1152*1024)   // 16*128*1089 f32

// ---------------- init: zero counters + feat ----------------
__global__ void init_zero(unsigned* cnt2, unsigned* cnt1, float* feat) {
    int i = blockIdx.x * 256 + threadIdx.x;
    if (i < 16*4096) cnt2[i] = 0u;
    if (i < 16*8) cnt1[i] = 0u;
    if (i < 16*1024) feat[i] = 0.f;
}

// ---------------- histograms ----------------
__global__ __launch_bounds__(256) void hist_kernel(const float* __restrict__ x1,
                                                   unsigned* __restrict__ cnt2,
                                                   unsigned* __restrict__ cnt1) {
    int b = blockIdx.y;
    __shared__ unsigned h2[4096];
    __shared__ unsigned h1[8];
    for (int i = threadIdx.x; i < 4096; i += 256) h2[i] = 0u;
    if (threadIdx.x < 8) h1[threadIdx.x] = 0u;
    __syncthreads();

    const float* L  = x1 + (size_t)b * 3 * HW;
    const float* A  = L + HW;
    const float* Bc = A + HW;
    int start = blockIdx.x * (HW / 64);     // grid.x = 64
    int cnt   = HW / 64;
    for (int i = threadIdx.x; i < cnt; i += 256) {
        int pix = start + i;
        float l = L[pix], a = A[pix], bb = Bc[pix];
        float va = (a + 1.f) * 0.5f;
        float vb = (bb + 1.f) * 0.5f;
        if (a != 0.f && bb != 0.f && va >= 0.f && va <= 1.f && vb >= 0.f && vb <= 1.f) {
            int ia = min(max((int)floorf(va * 64.f), 0), 63);
            int ib = min(max((int)floorf(vb * 64.f), 0), 63);
            atomicAdd(&h2[ia * 64 + ib], 1u);
        }
        float vl = (l + 1.f) * 0.5f;
        if (l != 0.f && vl >= 0.f && vl <= 1.f) {
            int il = min(max((int)floorf(vl * 8.f), 0), 7);
            atomicAdd(&h1[il], 1u);
        }
    }
    __syncthreads();
    for (int i = threadIdx.x; i < 4096; i += 256)
        if (h2[i]) atomicAdd(&cnt2[b * 4096 + i], h2[i]);
    if (threadIdx.x < 8 && h1[threadIdx.x]) atomicAdd(&cnt1[b * 8 + threadIdx.x], h1[threadIdx.x]);
}

// normalize + transpose (ref does swapaxes(1,2)); also 1D hist normalize
__global__ __launch_bounds__(256) void hist_norm(const unsigned* __restrict__ cnt2,
                                                 const unsigned* __restrict__ cnt1,
                                                 float* __restrict__ hab,
                                                 float* __restrict__ hl) {
    int b = blockIdx.x;
    __shared__ float red[256];
    unsigned s = 0;
    for (int i = threadIdx.x; i < 4096; i += 256) s += cnt2[b * 4096 + i];
    red[threadIdx.x] = (float)s;
    __syncthreads();
    for (int off = 128; off > 0; off >>= 1) {
        if (threadIdx.x < off) red[threadIdx.x] += red[threadIdx.x + off];
        __syncthreads();
    }
    float inv2 = 1.f / red[0];
    // hab[b, r, c] = cnt2[b, ia=c, ib=r] / tot   (transpose)
    for (int i = threadIdx.x; i < 4096; i += 256) {
        int r = i >> 6, c = i & 63;
        hab[b * 4096 + i] = (float)cnt2[b * 4096 + c * 64 + r] * inv2;
    }
    if (threadIdx.x < 8) {
        unsigned t = 0;
        for (int k = 0; k < 8; ++k) t += cnt1[b * 8 + k];
        hl[b * 8 + threadIdx.x] = (float)cnt1[b * 8 + threadIdx.x] / (float)t;
    }
}

// ---------------- conv1 (1x1, pad->66) + BN + maxpool(3,2,1) + relu ----------------
// channels 1..8 of hist_inp are spatially constant => conv = w1[oc,0]*H(r,c) + Kc
__global__ __launch_bounds__(256) void conv1_pool(const float* __restrict__ hab,
                                                  const float* __restrict__ hl,
                                                  const float* __restrict__ w1,
                                                  const float* __restrict__ g1,
                                                  const float* __restrict__ b1v,
                                                  const float* __restrict__ m1,
                                                  const float* __restrict__ v1,
                                                  float* __restrict__ zout) {
    int oc = blockIdx.x, b = blockIdx.y;
    __shared__ float Hs[4096];
    for (int i = threadIdx.x; i < 4096; i += 256) Hs[i] = hab[b * 4096 + i];

    float inv   = g1[oc] * rsqrtf(v1[oc] + 1e-5f);
    float shift = b1v[oc] - m1[oc] * inv;
    float Kc = 0.f;
#pragma unroll
    for (int c = 1; c < 9; ++c) Kc = fmaf(w1[oc * 9 + c], hl[b * 8 + c - 1], Kc);
    float a_lin = w1[oc * 9 + 0] * inv;
    float c_lin = fmaf(Kc, inv, shift);
    __syncthreads();

    for (int o = threadIdx.x; o < M_SP; o += 256) {
        int p = o / 33, q = o - p * 33;
        float mx = -INFINITY;
#pragma unroll
        for (int dy = -1; dy <= 1; ++dy) {
            int yi = 2 * p + dy;
            if (yi < 0 || yi > 65) continue;
#pragma unroll
            for (int dx = -1; dx <= 1; ++dx) {
                int yj = 2 * q + dx;
                if (yj < 0 || yj > 65) continue;
                float val;
                if (yi == 0 || yi == 65 || yj == 0 || yj == 65)
                    val = shift;   // conv of zero-padding = 0, then BN shift
                else
                    val = fmaf(a_lin, Hs[(yi - 1) * 64 + (yj - 1)], c_lin);
                mx = fmaxf(mx, val);
            }
        }
        zout[((b * 128 + oc) * 33 + p) * 33 + q] = fmaxf(mx, 0.f);
    }
}

// ---------------- w2 [1024,1152] -> w2t [1152,1024] ----------------
__global__ void w2_transpose(const float* __restrict__ w2, float* __restrict__ w2t) {
    __shared__ float tile[32][33];
    int kb = blockIdx.x * 32, ob = blockIdx.y * 32;
    int tx = threadIdx.x, ty = threadIdx.y;   // 32 x 8
#pragma unroll
    for (int i = 0; i < 32; i += 8)
        tile[ty + i][tx] = w2[(size_t)(ob + ty + i) * K2 + kb + tx];
    __syncthreads();
#pragma unroll
    for (int i = 0; i < 32; i += 8)
        w2t[(size_t)(kb + ty + i) * 1024 + ob + tx] = tile[tx][ty + i];
}

// ---------------- conv2 implicit GEMM (per batch): M=1089 N=1024 K=1152 ----------------
// fused BN2 + ReLU + spatial mean -> atomicAdd into feat[b,oc]
#define KT 16
__global__ __launch_bounds__(256) void conv2_gemm(const float* __restrict__ z,
                                                  const float* __restrict__ w2t,
                                                  const float* __restrict__ g2,
                                                  const float* __restrict__ b2v,
                                                  const float* __restrict__ m2,
                                                  const float* __restrict__ v2,
                                                  float* __restrict__ feat) {
    int b = blockIdx.z;
    int mbase = blockIdx.y * 128;
    int nbase = blockIdx.x * 128;
    __shared__ float As[KT][128];
    __shared__ float Bs[KT][128];
    int tid = threadIdx.x;
    int tx = tid & 15, ty = tid >> 4;

    float acc[8][8];
#pragma unroll
    for (int i = 0; i < 8; ++i)
#pragma unroll
        for (int j = 0; j < 8; ++j) acc[i][j] = 0.f;

    const float* zb = z + (size_t)b * 128 * M_SP;
    int ml = tid & 127;
    int khalf = tid >> 7;   // 0 or 1
    int m = mbase + ml;
    int p = m / 33, q = m - p * 33;
    bool mvalid = (m < M_SP);

    for (int kt = 0; kt < K2; kt += KT) {
        // As[k][m]: im2col gather
#pragma unroll
        for (int kk = 0; kk < KT; kk += 2) {
            int k = kt + kk + khalf;
            int ic = k / 9;
            int r9 = k - ic * 9;
            int kh = r9 / 3;
            int kw = r9 - kh * 3;
            int pr = p + kh - 1, pc = q + kw - 1;
            float v = 0.f;
            if (mvalid && pr >= 0 && pr < 33 && pc >= 0 && pc < 33)
                v = zb[(ic * 33 + pr) * 33 + pc];
            As[kk + khalf][ml] = v;
        }
        // Bs[k][n]
#pragma unroll
        for (int kk = 0; kk < KT; kk += 2) {
            int k = kt + kk + khalf;
            Bs[kk + khalf][ml] = w2t[k * 1024 + nbase + ml];
        }
        __syncthreads();
#pragma unroll
        for (int k = 0; k < KT; ++k) {
            float4 a0 = *(const float4*)&As[k][ty * 4];
            float4 a1 = *(const float4*)&As[k][64 + ty * 4];
            float4 b0 = *(const float4*)&Bs[k][tx * 4];
            float4 b1 = *(const float4*)&Bs[k][64 + tx * 4];
            float a[8] = {a0.x, a0.y, a0.z, a0.w, a1.x, a1.y, a1.z, a1.w};
            float bb[8] = {b0.x, b0.y, b0.z, b0.w, b1.x, b1.y, b1.z, b1.w};
#pragma unroll
            for (int i = 0; i < 8; ++i)
#pragma unroll
                for (int j = 0; j < 8; ++j)
                    acc[i][j] = fmaf(a[i], bb[j], acc[i][j]);
        }
        __syncthreads();
    }

    // epilogue: BN2 + ReLU + column partial sums (mean fused)
    float partial[8];
#pragma unroll
    for (int j = 0; j < 8; ++j) {
        int cl = tx * 4 + (j & 3) + (j >> 2) * 64;
        int n = nbase + cl;
        float inv = g2[n] * rsqrtf(v2[n] + 1e-5f);
        float sh  = b2v[n] - m2[n] * inv;
        float s = 0.f;
#pragma unroll
        for (int i = 0; i < 8; ++i) {
            int mm = mbase + ty * 4 + (i & 3) + (i >> 2) * 64;
            if (mm < M_SP) s += fmaxf(fmaf(acc[i][j], inv, sh), 0.f);
        }
        partial[j] = s;
    }
    float* red = &As[0][0];   // 2048 floats, safe after final sync
#pragma unroll
    for (int j = 0; j < 8; ++j) {
        int cl = tx * 4 + (j & 3) + (j >> 2) * 64;
        red[ty * 128 + cl] = partial[j];
    }
    __syncthreads();
    if (tid < 128) {
        float s = 0.f;
#pragma unroll
        for (int t = 0; t < 16; ++t) s += red[t * 128 + tid];
        atomicAdd(&feat[b * 1024 + nbase + tid], s * (1.f / 1089.f));
    }
}

// ---------------- head: copy x, linear ----------------
__global__ void copy_x(const float* __restrict__ x, float* __restrict__ out) {
    int i = blockIdx.x * 256 + threadIdx.x;
    if (i < 16 * 2048) {
        int b = i >> 11, j = i & 2047;
        out[b * 2304 + j] = x[i];
    }
}

__global__ void linear_head(const float* __restrict__ feat, const float* __restrict__ wl,
                            const float* __restrict__ bl, float* __restrict__ out) {
    int j = blockIdx.x, b = blockIdx.y;
    int lane = threadIdx.x;   // 64
    const float* f = feat + b * 1024;
    const float* w = wl + j * 1024;
    float s = 0.f;
    for (int k = lane; k < 1024; k += 64) s = fmaf(f[k], w[k], s);
#pragma unroll
    for (int off = 32; off > 0; off >>= 1) s += __shfl_down(s, off);
    if (lane == 0) out[b * 2304 + 2048 + j] = s + bl[j];
}

extern "C" void kernel_launch(void* const* d_in, const int* in_sizes, int n_in,
                              void* d_out, int out_size, void* d_ws, size_t ws_size,
                              hipStream_t stream) {
    const float* x  = (const float*)d_in[0];
    const float* x1 = (const float*)d_in[1];
    const float* w1 = (const float*)d_in[2];
    const float* g1 = (const float*)d_in[3];
    const float* b1 = (const float*)d_in[4];
    const float* m1 = (const float*)d_in[5];
    const float* v1 = (const float*)d_in[6];
    const float* w2 = (const float*)d_in[7];
    const float* g2 = (const float*)d_in[8];
    const float* b2 = (const float*)d_in[9];
    const float* m2 = (const float*)d_in[10];
    const float* v2 = (const float*)d_in[11];
    const float* wl = (const float*)d_in[12];
    const float* bl = (const float*)d_in[13];
    float* out = (float*)d_out;

    float* wsf = (float*)d_ws;
    unsigned* cnt2 = (unsigned*)(wsf + OFF_CNT2);
    unsigned* cnt1 = (unsigned*)(wsf + OFF_CNT1);
    float* hab  = wsf + OFF_HAB;
    float* hl   = wsf + OFF_HL;
    float* feat = wsf + OFF_FEAT;
    float* w2t  = wsf + OFF_W2T;
    float* z    = wsf + OFF_Z;

    init_zero<<<(16 * 4096 + 255) / 256, 256, 0, stream>>>(cnt2, cnt1, feat);
    hist_kernel<<<dim3(64, 16), 256, 0, stream>>>(x1, cnt2, cnt1);
    hist_norm<<<16, 256, 0, stream>>>(cnt2, cnt1, hab, hl);
    conv1_pool<<<dim3(128, 16), 256, 0, stream>>>(hab, hl, w1, g1, b1, m1, v1, z);
    w2_transpose<<<dim3(36, 32), dim3(32, 8), 0, stream>>>(w2, w2t);
    conv2_gemm<<<dim3(8, 9, 16), 256, 0, stream>>>(z, w2t, g2, b2, m2, v2, feat);
    copy_x<<<(16 * 2048 + 255) / 256, 256, 0, stream>>>(x, out);
    linear_head<<<dim3(256, 16), 64, 0, stream>>>(feat, wl, bl, out);
}

// Round 3
// 138.735 us; speedup vs baseline: 4.6955x; 4.6955x over previous
//
#include <hip/hip_runtime.h>
#include <hip/hip_bf16.h>
#include <math.h>

typedef __attribute__((ext_vector_type(8))) short bf16x8;
typedef __attribute__((ext_vector_type(4))) float f32x4;

#define HW 262144        // 512*512
#define M_SP 1089        // 33*33

// ---- ws layout in 4-byte words ----
#define OFF_CNT2 0                        // 16*4096 u32
#define OFF_CNT1 (OFF_CNT2 + 16*4096)     // 512
#define OFF_HAB  (OFF_CNT1 + 512)         // 16*4096 f32
#define OFF_HL   (OFF_HAB + 16*4096)      // 512
#define OFF_FEAT (OFF_HL + 512)           // 16*1024 f32
#define OFF_W2R  (OFF_FEAT + 16*1024)     // bf16[9][1024][128] = 589824 words
#define OFF_ZT   (OFF_W2R + 589824)       // bf16[16][37][35][128] = 1326080 words
#define ZT_WORDS 1326080

// ---------------- init ----------------
__global__ void init_zero(unsigned* cnt2, unsigned* cnt1, float* feat, unsigned* ztw) {
    int i = blockIdx.x * 256 + threadIdx.x;
    if (i < ZT_WORDS) ztw[i] = 0u;
    if (i < 16 * 4096) cnt2[i] = 0u;
    if (i < 512) cnt1[i] = 0u;
    if (i < 16 * 1024) feat[i] = 0.f;
}

// ---------------- histograms ----------------
__device__ inline unsigned wred_u32(unsigned v) {
#pragma unroll
    for (int off = 32; off > 0; off >>= 1) v += __shfl_down(v, off);
    return v;
}

__global__ __launch_bounds__(256) void hist_kernel(const float* __restrict__ x1,
                                                   unsigned* __restrict__ cnt2,
                                                   unsigned* __restrict__ cnt1) {
    int b = blockIdx.y;
    __shared__ unsigned h2[4096];
    for (int i = threadIdx.x; i < 4096; i += 256) h2[i] = 0u;
    __syncthreads();

    const float* L  = x1 + (size_t)b * 3 * HW;
    const float* A  = L + HW;
    const float* Bc = A + HW;
    int start = blockIdx.x * (HW / 64);
    unsigned c0=0,c1=0,c2=0,c3=0,c4=0,c5=0,c6=0,c7=0;
    for (int i = threadIdx.x; i < HW / 64; i += 256) {
        int pix = start + i;
        float l = L[pix], a = A[pix], bb = Bc[pix];
        float va = (a + 1.f) * 0.5f;
        float vb = (bb + 1.f) * 0.5f;
        if (a != 0.f && bb != 0.f && va >= 0.f && va <= 1.f && vb >= 0.f && vb <= 1.f) {
            int ia = min(max((int)floorf(va * 64.f), 0), 63);
            int ib = min(max((int)floorf(vb * 64.f), 0), 63);
            atomicAdd(&h2[ia * 64 + ib], 1u);
        }
        float vl = (l + 1.f) * 0.5f;
        if (l != 0.f && vl >= 0.f && vl <= 1.f) {
            int il = min(max((int)floorf(vl * 8.f), 0), 7);
            c0 += (il == 0); c1 += (il == 1); c2 += (il == 2); c3 += (il == 3);
            c4 += (il == 4); c5 += (il == 5); c6 += (il == 6); c7 += (il == 7);
        }
    }
    c0 = wred_u32(c0); c1 = wred_u32(c1); c2 = wred_u32(c2); c3 = wred_u32(c3);
    c4 = wred_u32(c4); c5 = wred_u32(c5); c6 = wred_u32(c6); c7 = wred_u32(c7);
    if ((threadIdx.x & 63) == 0) {
        if (c0) atomicAdd(&cnt1[b * 8 + 0], c0);
        if (c1) atomicAdd(&cnt1[b * 8 + 1], c1);
        if (c2) atomicAdd(&cnt1[b * 8 + 2], c2);
        if (c3) atomicAdd(&cnt1[b * 8 + 3], c3);
        if (c4) atomicAdd(&cnt1[b * 8 + 4], c4);
        if (c5) atomicAdd(&cnt1[b * 8 + 5], c5);
        if (c6) atomicAdd(&cnt1[b * 8 + 6], c6);
        if (c7) atomicAdd(&cnt1[b * 8 + 7], c7);
    }
    __syncthreads();
    for (int i = threadIdx.x; i < 4096; i += 256)
        if (h2[i]) atomicAdd(&cnt2[b * 4096 + i], h2[i]);
}

__global__ __launch_bounds__(256) void hist_norm(const unsigned* __restrict__ cnt2,
                                                 const unsigned* __restrict__ cnt1,
                                                 float* __restrict__ hab,
                                                 float* __restrict__ hl) {
    int b = blockIdx.x;
    __shared__ float red[256];
    unsigned s = 0;
    for (int i = threadIdx.x; i < 4096; i += 256) s += cnt2[b * 4096 + i];
    red[threadIdx.x] = (float)s;
    __syncthreads();
    for (int off = 128; off > 0; off >>= 1) {
        if (threadIdx.x < off) red[threadIdx.x] += red[threadIdx.x + off];
        __syncthreads();
    }
    float inv2 = 1.f / red[0];
    for (int i = threadIdx.x; i < 4096; i += 256) {
        int r = i >> 6, c = i & 63;
        hab[b * 4096 + i] = (float)cnt2[b * 4096 + c * 64 + r] * inv2;
    }
    if (threadIdx.x < 8) {
        unsigned t = 0;
        for (int k = 0; k < 8; ++k) t += cnt1[b * 8 + k];
        hl[b * 8 + threadIdx.x] = (float)cnt1[b * 8 + threadIdx.x] / (float)t;
    }
}

// ---------------- w2 [1024][128][3][3] -> w2r[tap][oc][ic] bf16 ----------------
__global__ void w2_prep(const float* __restrict__ w2, __hip_bfloat16* __restrict__ w2r) {
    int i = blockIdx.x * 256 + threadIdx.x;
    if (i < 9 * 1024 * 128) {
        int tap = i >> 17;
        int rem = i & 131071;
        int oc = rem >> 7, ic = rem & 127;
        w2r[i] = __float2bfloat16(w2[oc * 1152 + ic * 9 + tap]);
    }
}

// ---------------- conv1 + BN + maxpool + relu -> zt[b][37][35][128] bf16 (halo zeroed) --------
__global__ __launch_bounds__(256) void conv1_pool(
    const float* __restrict__ hab, const float* __restrict__ hl,
    const float* __restrict__ w1, const float* __restrict__ g1,
    const float* __restrict__ b1v, const float* __restrict__ m1,
    const float* __restrict__ v1, __hip_bfloat16* __restrict__ zt)
{
    const int p = blockIdx.x;   // 0..32
    const int b = blockIdx.y;
    __shared__ float aL[128], cL[128], sL[128];
    __shared__ float Hrow[3][64];
    __shared__ float qmx[33], qmn[33];
    __shared__ int qbd[33];
    const int tid = threadIdx.x;
    if (tid < 128) {
        int oc = tid;
        float inv = g1[oc] * rsqrtf(v1[oc] + 1e-5f);
        float s = b1v[oc] - m1[oc] * inv;
        float Kc = 0.f;
#pragma unroll
        for (int c = 1; c < 9; ++c) Kc = fmaf(w1[oc * 9 + c], hl[b * 8 + c - 1], Kc);
        aL[oc] = w1[oc * 9] * inv;
        cL[oc] = fmaf(Kc, inv, s);
        sL[oc] = s;
    }
    if (tid < 192) {             // FIX: was (tid>=128 && tid<320) -> Hrow[2] never loaded
        int rr = tid >> 6, cc = tid & 63;
        int row = 2 * p - 2 + rr;
        Hrow[rr][cc] = (row >= 0 && row < 64) ? hab[b * 4096 + row * 64 + cc] : 0.f;
    }
    __syncthreads();
    if (tid < 33) {
        int q = tid;
        float mx = -1e30f, mn = 1e30f;
        int bd = 0;
#pragma unroll
        for (int dy = 0; dy < 3; ++dy) {
            int yi = 2 * p - 1 + dy;
            if (yi < 0 || yi > 65) continue;
#pragma unroll
            for (int dx = 0; dx < 3; ++dx) {
                int yj = 2 * q - 1 + dx;
                if (yj < 0 || yj > 65) continue;
                if (yi == 0 || yi == 65 || yj == 0 || yj == 65) bd = 1;
                else {
                    float h = Hrow[dy][2 * q - 2 + dx];
                    mx = fmaxf(mx, h); mn = fminf(mn, h);
                }
            }
        }
        qmx[q] = mx; qmn[q] = mn; qbd[q] = bd;
    }
    __syncthreads();
    __hip_bfloat16* zrow = zt + (((size_t)b * 37 + (p + 1)) * 35 + 1) * 128;
    for (int it = tid; it < 33 * 128; it += 256) {
        int q = it >> 7, oc = it & 127;
        float a = aL[oc];
        float v = fmaf(a, (a > 0.f ? qmx[q] : qmn[q]), cL[oc]);
        if (qbd[q]) v = fmaxf(v, sL[oc]);
        v = fmaxf(v, 0.f);
        zrow[q * 128 + oc] = __float2bfloat16(v);
    }
}

// ---------------- conv2 as 9 tap-GEMMs, bf16 MFMA, fused BN+ReLU+mean ----------------
__global__ __launch_bounds__(256, 2) void conv2_mfma(
        const __hip_bfloat16* __restrict__ zt,
        const __hip_bfloat16* __restrict__ w2r,
        const float* __restrict__ g2, const float* __restrict__ b2v,
        const float* __restrict__ m2, const float* __restrict__ v2,
        float* __restrict__ feat)
{
    __shared__ char lds[65536];   // 2 buffers x (A 16KB + B 16KB)
    const int tid = threadIdx.x;
    const int lane = tid & 63, wid = tid >> 6;
    const int b = blockIdx.z;
    const int nbase = blockIdx.x * 128;
    const int mbase = blockIdx.y * 128;
    const int lr16 = lane & 15, lk = lane >> 4;
    const int wm = (wid >> 1) * 64, wn = (wid & 1) * 64;

    const int slot = lane & 7, rr8 = lane >> 3;
    const char* aS[4];
    const char* bS[4];
    {
        const char* ztb = (const char*)zt + (size_t)b * (37 * 35 * 128 * 2);
#pragma unroll
        for (int v = 0; v < 4; ++v) {
            int r = wid * 32 + v * 8 + rr8;
            int sl = (slot ^ (r & 7)) << 4;
            int m = mbase + r;
            int p = m / 33, q = m - p * 33;
            aS[v] = ztb + (p * 35 + q) * 256 + sl;
            bS[v] = (const char*)w2r + (size_t)(nbase + r) * 256 + sl;
        }
    }

    f32x4 acc[4][4];
#pragma unroll
    for (int i = 0; i < 4; ++i)
#pragma unroll
        for (int j = 0; j < 4; ++j) acc[i][j] = (f32x4){0.f, 0.f, 0.f, 0.f};

    auto stage = [&](int d, int s) {
        const int tap = s >> 1, kby = (s & 1) << 7;
        const int kh = tap / 3, kw = tap - kh * 3;
        const int aoff = (kh * 35 + kw) * 256 + kby;
        const int boff = tap * 262144 + kby;
        char* ab = lds + d * 32768 + wid * 4096;
        char* bb = ab + 16384;
#pragma unroll
        for (int v = 0; v < 4; ++v)
            __builtin_amdgcn_global_load_lds(
                (const __attribute__((address_space(1))) unsigned int*)(aS[v] + aoff),
                (__attribute__((address_space(3))) unsigned int*)(ab + v * 1024), 16, 0, 0);
#pragma unroll
        for (int v = 0; v < 4; ++v)
            __builtin_amdgcn_global_load_lds(
                (const __attribute__((address_space(1))) unsigned int*)(bS[v] + boff),
                (__attribute__((address_space(3))) unsigned int*)(bb + v * 1024), 16, 0, 0);
    };

    auto compute = [&](int d) {
        const char* Ab = lds + d * 32768;
        const char* Bb = Ab + 16384;
#pragma unroll
        for (int ks = 0; ks < 2; ++ks) {
            bf16x8 af[4], bfr[4];
#pragma unroll
            for (int i = 0; i < 4; ++i) {
                int row = wm + i * 16 + lr16;
                af[i] = *(const bf16x8*)(Ab + row * 128 + (((ks * 4 + lk) ^ (row & 7)) << 4));
            }
#pragma unroll
            for (int j = 0; j < 4; ++j) {
                int row = wn + j * 16 + lr16;
                bfr[j] = *(const bf16x8*)(Bb + row * 128 + (((ks * 4 + lk) ^ (row & 7)) << 4));
            }
#pragma unroll
            for (int i = 0; i < 4; ++i)
#pragma unroll
                for (int j = 0; j < 4; ++j)
                    acc[i][j] = __builtin_amdgcn_mfma_f32_16x16x32_bf16(af[i], bfr[j], acc[i][j], 0, 0, 0);
        }
    };

    stage(0, 0);
    __syncthreads();
#pragma unroll 1
    for (int s = 0; s < 18; ++s) {
        if (s < 17) stage((s + 1) & 1, s + 1);
        compute(s & 1);
        __syncthreads();
    }

    float* red = (float*)lds;
#pragma unroll
    for (int j = 0; j < 4; ++j) {
        int nl = wn + j * 16 + lr16;
        int n = nbase + nl;
        float inv = g2[n] * rsqrtf(v2[n] + 1e-5f);
        float sh = b2v[n] - m2[n] * inv;
        float ssum = 0.f;
#pragma unroll
        for (int i = 0; i < 4; ++i) {
            int mlb = wm + i * 16 + lk * 4;
#pragma unroll
            for (int r = 0; r < 4; ++r) {
                if (mbase + mlb + r < M_SP)
                    ssum += fmaxf(fmaf(acc[i][j][r], inv, sh), 0.f);
            }
        }
        red[((wid >> 1) * 4 + lk) * 128 + nl] = ssum;
    }
    __syncthreads();
    if (tid < 128) {
        float s = 0.f;
#pragma unroll
        for (int c = 0; c < 8; ++c) s += red[c * 128 + tid];
        atomicAdd(&feat[b * 1024 + nbase + tid], s * (1.f / 1089.f));
    }
}

// ---------------- head ----------------
__global__ void copy_x(const float* __restrict__ x, float* __restrict__ out) {
    int i = blockIdx.x * 256 + threadIdx.x;
    if (i < 16 * 2048) {
        int b = i >> 11, j = i & 2047;
        out[b * 2304 + j] = x[i];
    }
}

__global__ void linear_head(const float* __restrict__ feat, const float* __restrict__ wl,
                            const float* __restrict__ bl, float* __restrict__ out) {
    int j = blockIdx.x, b = blockIdx.y;
    int lane = threadIdx.x;   // 64
    const float* f = feat + b * 1024;
    const float* w = wl + j * 1024;
    float s = 0.f;
    for (int k = lane; k < 1024; k += 64) s = fmaf(f[k], w[k], s);
#pragma unroll
    for (int off = 32; off > 0; off >>= 1) s += __shfl_down(s, off);
    if (lane == 0) out[b * 2304 + 2048 + j] = s + bl[j];
}

extern "C" void kernel_launch(void* const* d_in, const int* in_sizes, int n_in,
                              void* d_out, int out_size, void* d_ws, size_t ws_size,
                              hipStream_t stream) {
    const float* x  = (const float*)d_in[0];
    const float* x1 = (const float*)d_in[1];
    const float* w1 = (const float*)d_in[2];
    const float* g1 = (const float*)d_in[3];
    const float* b1 = (const float*)d_in[4];
    const float* m1 = (const float*)d_in[5];
    const float* v1 = (const float*)d_in[6];
    const float* w2 = (const float*)d_in[7];
    const float* g2 = (const float*)d_in[8];
    const float* b2 = (const float*)d_in[9];
    const float* m2 = (const float*)d_in[10];
    const float* v2 = (const float*)d_in[11];
    const float* wl = (const float*)d_in[12];
    const float* bl = (const float*)d_in[13];
    float* out = (float*)d_out;

    float* wsf = (float*)d_ws;
    unsigned* cnt2 = (unsigned*)(wsf + OFF_CNT2);
    unsigned* cnt1 = (unsigned*)(wsf + OFF_CNT1);
    float* hab  = wsf + OFF_HAB;
    float* hl   = wsf + OFF_HL;
    float* feat = wsf + OFF_FEAT;
    __hip_bfloat16* w2r = (__hip_bfloat16*)(wsf + OFF_W2R);
    __hip_bfloat16* zt  = (__hip_bfloat16*)(wsf + OFF_ZT);

    init_zero<<<(ZT_WORDS + 255) / 256, 256, 0, stream>>>(cnt2, cnt1, feat, (unsigned*)zt);
    hist_kernel<<<dim3(64, 16), 256, 0, stream>>>(x1, cnt2, cnt1);
    hist_norm<<<16, 256, 0, stream>>>(cnt2, cnt1, hab, hl);
    conv1_pool<<<dim3(33, 16), 256, 0, stream>>>(hab, hl, w1, g1, b1, m1, v1, zt);
    w2_prep<<<(9 * 1024 * 128 + 255) / 256, 256, 0, stream>>>(w2, w2r);
    conv2_mfma<<<dim3(8, 9, 16), 256, 0, stream>>>(zt, w2r, g2, b2, m2, v2, feat);
    copy_x<<<(16 * 2048 + 255) / 256, 256, 0, stream>>>(x, out);
    linear_head<<<dim3(256, 16), 64, 0, stream>>>(feat, wl, bl, out);
}

// Round 4
// 136.515 us; speedup vs baseline: 4.7718x; 1.0163x over previous
//
#include <hip/hip_runtime.h>
#include <hip/hip_bf16.h>
#include <math.h>

typedef __attribute__((ext_vector_type(8))) short bf16x8;
typedef __attribute__((ext_vector_type(4))) float f32x4;

#define HW 262144        // 512*512
#define M_SP 1089        // 33*33

// ---- ws layout in 4-byte words ----
#define OFF_CNT2 0                        // 16*4096 u32
#define OFF_CNT1 (OFF_CNT2 + 16*4096)     // 512
#define OFF_HAB  (OFF_CNT1 + 512)         // 16*4096 f32
#define OFF_HL   (OFF_HAB + 16*4096)      // 512
#define OFF_FEAT (OFF_HL + 512)           // 16*1024 f32
#define OFF_W2R  (OFF_FEAT + 16*1024)     // bf16[9][1024][128] = 589824 words
#define OFF_ZT   (OFF_W2R + 589824)       // bf16[16][37][35][128] = 1326080 words
#define ZT_WORDS 1326080

// ---------------- init ----------------
__global__ void init_zero(unsigned* cnt2, unsigned* cnt1, float* feat, unsigned* ztw) {
    int i = blockIdx.x * 256 + threadIdx.x;
    if (i < ZT_WORDS) ztw[i] = 0u;
    if (i < 16 * 4096) cnt2[i] = 0u;
    if (i < 512) cnt1[i] = 0u;
    if (i < 16 * 1024) feat[i] = 0.f;
}

// ---------------- histograms ----------------
__device__ inline unsigned wred_u32(unsigned v) {
#pragma unroll
    for (int off = 32; off > 0; off >>= 1) v += __shfl_down(v, off);
    return v;
}

__global__ __launch_bounds__(256) void hist_kernel(const float* __restrict__ x1,
                                                   unsigned* __restrict__ cnt2,
                                                   unsigned* __restrict__ cnt1) {
    int b = blockIdx.y;
    __shared__ unsigned h2[4096];
    for (int i = threadIdx.x; i < 4096; i += 256) h2[i] = 0u;
    __syncthreads();

    const float4* L4 = (const float4*)(x1 + (size_t)b * 3 * HW);
    const float4* A4 = (const float4*)(x1 + (size_t)b * 3 * HW + HW);
    const float4* B4 = (const float4*)(x1 + (size_t)b * 3 * HW + 2 * HW);
    const int start = blockIdx.x * 1024;   // float4 units; 1024 per block (grid.x=64)

    unsigned c0=0,c1=0,c2=0,c3=0,c4=0,c5=0,c6=0,c7=0;
#pragma unroll
    for (int it = 0; it < 4; ++it) {
        int idx = start + it * 256 + threadIdx.x;
        float4 l4 = L4[idx];
        float4 a4 = A4[idx];
        float4 b4 = B4[idx];
        const float lv[4] = {l4.x, l4.y, l4.z, l4.w};
        const float av[4] = {a4.x, a4.y, a4.z, a4.w};
        const float bv[4] = {b4.x, b4.y, b4.z, b4.w};
#pragma unroll
        for (int e = 0; e < 4; ++e) {
            float l = lv[e], a = av[e], bb = bv[e];
            float va = (a + 1.f) * 0.5f;
            float vb = (bb + 1.f) * 0.5f;
            if (a != 0.f && bb != 0.f && va >= 0.f && va <= 1.f && vb >= 0.f && vb <= 1.f) {
                int ia = min(max((int)floorf(va * 64.f), 0), 63);
                int ib = min(max((int)floorf(vb * 64.f), 0), 63);
                atomicAdd(&h2[ia * 64 + ib], 1u);
            }
            float vl = (l + 1.f) * 0.5f;
            if (l != 0.f && vl >= 0.f && vl <= 1.f) {
                int il = min(max((int)floorf(vl * 8.f), 0), 7);
                c0 += (il == 0); c1 += (il == 1); c2 += (il == 2); c3 += (il == 3);
                c4 += (il == 4); c5 += (il == 5); c6 += (il == 6); c7 += (il == 7);
            }
        }
    }
    c0 = wred_u32(c0); c1 = wred_u32(c1); c2 = wred_u32(c2); c3 = wred_u32(c3);
    c4 = wred_u32(c4); c5 = wred_u32(c5); c6 = wred_u32(c6); c7 = wred_u32(c7);
    if ((threadIdx.x & 63) == 0) {
        if (c0) atomicAdd(&cnt1[b * 8 + 0], c0);
        if (c1) atomicAdd(&cnt1[b * 8 + 1], c1);
        if (c2) atomicAdd(&cnt1[b * 8 + 2], c2);
        if (c3) atomicAdd(&cnt1[b * 8 + 3], c3);
        if (c4) atomicAdd(&cnt1[b * 8 + 4], c4);
        if (c5) atomicAdd(&cnt1[b * 8 + 5], c5);
        if (c6) atomicAdd(&cnt1[b * 8 + 6], c6);
        if (c7) atomicAdd(&cnt1[b * 8 + 7], c7);
    }
    __syncthreads();
    for (int i = threadIdx.x; i < 4096; i += 256)
        if (h2[i]) atomicAdd(&cnt2[b * 4096 + i], h2[i]);
}

__global__ __launch_bounds__(256) void hist_norm(const unsigned* __restrict__ cnt2,
                                                 const unsigned* __restrict__ cnt1,
                                                 float* __restrict__ hab,
                                                 float* __restrict__ hl) {
    int b = blockIdx.x;
    __shared__ float red[256];
    unsigned s = 0;
    for (int i = threadIdx.x; i < 4096; i += 256) s += cnt2[b * 4096 + i];
    red[threadIdx.x] = (float)s;
    __syncthreads();
    for (int off = 128; off > 0; off >>= 1) {
        if (threadIdx.x < off) red[threadIdx.x] += red[threadIdx.x + off];
        __syncthreads();
    }
    float inv2 = 1.f / red[0];
    for (int i = threadIdx.x; i < 4096; i += 256) {
        int r = i >> 6, c = i & 63;
        hab[b * 4096 + i] = (float)cnt2[b * 4096 + c * 64 + r] * inv2;
    }
    if (threadIdx.x < 8) {
        unsigned t = 0;
        for (int k = 0; k < 8; ++k) t += cnt1[b * 8 + k];
        hl[b * 8 + threadIdx.x] = (float)cnt1[b * 8 + threadIdx.x] / (float)t;
    }
}

// ---------------- w2 [1024][128][3][3] -> w2r[tap][oc][ic] bf16 ----------------
__global__ void w2_prep(const float* __restrict__ w2, __hip_bfloat16* __restrict__ w2r) {
    int i = blockIdx.x * 256 + threadIdx.x;
    if (i < 9 * 1024 * 128) {
        int tap = i >> 17;
        int rem = i & 131071;
        int oc = rem >> 7, ic = rem & 127;
        w2r[i] = __float2bfloat16(w2[oc * 1152 + ic * 9 + tap]);
    }
}

// ---------------- conv1 + BN + maxpool + relu -> zt[b][37][35][128] bf16 (halo zeroed) --------
__global__ __launch_bounds__(256) void conv1_pool(
    const float* __restrict__ hab, const float* __restrict__ hl,
    const float* __restrict__ w1, const float* __restrict__ g1,
    const float* __restrict__ b1v, const float* __restrict__ m1,
    const float* __restrict__ v1, __hip_bfloat16* __restrict__ zt)
{
    const int p = blockIdx.x;   // 0..32
    const int b = blockIdx.y;
    __shared__ float aL[128], cL[128], sL[128];
    __shared__ float Hrow[3][64];
    __shared__ float qmx[33], qmn[33];
    __shared__ int qbd[33];
    const int tid = threadIdx.x;
    if (tid < 128) {
        int oc = tid;
        float inv = g1[oc] * rsqrtf(v1[oc] + 1e-5f);
        float s = b1v[oc] - m1[oc] * inv;
        float Kc = 0.f;
#pragma unroll
        for (int c = 1; c < 9; ++c) Kc = fmaf(w1[oc * 9 + c], hl[b * 8 + c - 1], Kc);
        aL[oc] = w1[oc * 9] * inv;
        cL[oc] = fmaf(Kc, inv, s);
        sL[oc] = s;
    }
    if (tid < 192) {
        int rr = tid >> 6, cc = tid & 63;
        int row = 2 * p - 2 + rr;
        Hrow[rr][cc] = (row >= 0 && row < 64) ? hab[b * 4096 + row * 64 + cc] : 0.f;
    }
    __syncthreads();
    if (tid < 33) {
        int q = tid;
        float mx = -1e30f, mn = 1e30f;
        int bd = 0;
#pragma unroll
        for (int dy = 0; dy < 3; ++dy) {
            int yi = 2 * p - 1 + dy;
            if (yi < 0 || yi > 65) continue;
#pragma unroll
            for (int dx = 0; dx < 3; ++dx) {
                int yj = 2 * q - 1 + dx;
                if (yj < 0 || yj > 65) continue;
                if (yi == 0 || yi == 65 || yj == 0 || yj == 65) bd = 1;
                else {
                    float h = Hrow[dy][2 * q - 2 + dx];
                    mx = fmaxf(mx, h); mn = fminf(mn, h);
                }
            }
        }
        qmx[q] = mx; qmn[q] = mn; qbd[q] = bd;
    }
    __syncthreads();
    __hip_bfloat16* zrow = zt + (((size_t)b * 37 + (p + 1)) * 35 + 1) * 128;
    for (int it = tid; it < 33 * 128; it += 256) {
        int q = it >> 7, oc = it & 127;
        float a = aL[oc];
        float v = fmaf(a, (a > 0.f ? qmx[q] : qmn[q]), cL[oc]);
        if (qbd[q]) v = fmaxf(v, sL[oc]);
        v = fmaxf(v, 0.f);
        zrow[q * 128 + oc] = __float2bfloat16(v);
    }
}

// ---------------- conv2 as 9 tap-GEMMs, bf16 MFMA, fused BN+ReLU+mean ----------------
__global__ __launch_bounds__(256, 2) void conv2_mfma(
        const __hip_bfloat16* __restrict__ zt,
        const __hip_bfloat16* __restrict__ w2r,
        const float* __restrict__ g2, const float* __restrict__ b2v,
        const float* __restrict__ m2, const float* __restrict__ v2,
        float* __restrict__ feat)
{
    __shared__ char lds[65536];   // 2 buffers x (A 16KB + B 16KB)
    const int tid = threadIdx.x;
    const int lane = tid & 63, wid = tid >> 6;
    const int b = blockIdx.z;
    const int nbase = blockIdx.x * 128;
    const int mbase = blockIdx.y * 128;
    const int lr16 = lane & 15, lk = lane >> 4;
    const int wm = (wid >> 1) * 64, wn = (wid & 1) * 64;

    const int slot = lane & 7, rr8 = lane >> 3;
    const char* aS[4];
    const char* bS[4];
    {
        const char* ztb = (const char*)zt + (size_t)b * (37 * 35 * 128 * 2);
#pragma unroll
        for (int v = 0; v < 4; ++v) {
            int r = wid * 32 + v * 8 + rr8;
            int sl = (slot ^ (r & 7)) << 4;
            int m = mbase + r;
            int p = m / 33, q = m - p * 33;
            aS[v] = ztb + (p * 35 + q) * 256 + sl;
            bS[v] = (const char*)w2r + (size_t)(nbase + r) * 256 + sl;
        }
    }

    f32x4 acc[4][4];
#pragma unroll
    for (int i = 0; i < 4; ++i)
#pragma unroll
        for (int j = 0; j < 4; ++j) acc[i][j] = (f32x4){0.f, 0.f, 0.f, 0.f};

    auto stage = [&](int d, int s) {
        const int tap = s >> 1, kby = (s & 1) << 7;
        const int kh = tap / 3, kw = tap - kh * 3;
        const int aoff = (kh * 35 + kw) * 256 + kby;
        const int boff = tap * 262144 + kby;
        char* ab = lds + d * 32768 + wid * 4096;
        char* bb = ab + 16384;
#pragma unroll
        for (int v = 0; v < 4; ++v)
            __builtin_amdgcn_global_load_lds(
                (const __attribute__((address_space(1))) unsigned int*)(aS[v] + aoff),
                (__attribute__((address_space(3))) unsigned int*)(ab + v * 1024), 16, 0, 0);
#pragma unroll
        for (int v = 0; v < 4; ++v)
            __builtin_amdgcn_global_load_lds(
                (const __attribute__((address_space(1))) unsigned int*)(bS[v] + boff),
                (__attribute__((address_space(3))) unsigned int*)(bb + v * 1024), 16, 0, 0);
    };

    auto compute = [&](int d) {
        const char* Ab = lds + d * 32768;
        const char* Bb = Ab + 16384;
#pragma unroll
        for (int ks = 0; ks < 2; ++ks) {
            bf16x8 af[4], bfr[4];
#pragma unroll
            for (int i = 0; i < 4; ++i) {
                int row = wm + i * 16 + lr16;
                af[i] = *(const bf16x8*)(Ab + row * 128 + (((ks * 4 + lk) ^ (row & 7)) << 4));
            }
#pragma unroll
            for (int j = 0; j < 4; ++j) {
                int row = wn + j * 16 + lr16;
                bfr[j] = *(const bf16x8*)(Bb + row * 128 + (((ks * 4 + lk) ^ (row & 7)) << 4));
            }
#pragma unroll
            for (int i = 0; i < 4; ++i)
#pragma unroll
                for (int j = 0; j < 4; ++j)
                    acc[i][j] = __builtin_amdgcn_mfma_f32_16x16x32_bf16(af[i], bfr[j], acc[i][j], 0, 0, 0);
        }
    };

    stage(0, 0);
    __syncthreads();
#pragma unroll 1
    for (int s = 0; s < 18; ++s) {
        if (s < 17) stage((s + 1) & 1, s + 1);
        compute(s & 1);
        __syncthreads();
    }

    float* red = (float*)lds;
#pragma unroll
    for (int j = 0; j < 4; ++j) {
        int nl = wn + j * 16 + lr16;
        int n = nbase + nl;
        float inv = g2[n] * rsqrtf(v2[n] + 1e-5f);
        float sh = b2v[n] - m2[n] * inv;
        float ssum = 0.f;
#pragma unroll
        for (int i = 0; i < 4; ++i) {
            int mlb = wm + i * 16 + lk * 4;
#pragma unroll
            for (int r = 0; r < 4; ++r) {
                if (mbase + mlb + r < M_SP)
                    ssum += fmaxf(fmaf(acc[i][j][r], inv, sh), 0.f);
            }
        }
        red[((wid >> 1) * 4 + lk) * 128 + nl] = ssum;
    }
    __syncthreads();
    if (tid < 128) {
        float s = 0.f;
#pragma unroll
        for (int c = 0; c < 8; ++c) s += red[c * 128 + tid];
        atomicAdd(&feat[b * 1024 + nbase + tid], s * (1.f / 1089.f));
    }
}

// ---------------- head ----------------
__global__ void copy_x(const float* __restrict__ x, float* __restrict__ out) {
    int i = blockIdx.x * 256 + threadIdx.x;
    if (i < 16 * 2048) {
        int b = i >> 11, j = i & 2047;
        out[b * 2304 + j] = x[i];
    }
}

__global__ void linear_head(const float* __restrict__ feat, const float* __restrict__ wl,
                            const float* __restrict__ bl, float* __restrict__ out) {
    int j = blockIdx.x, b = blockIdx.y;
    int lane = threadIdx.x;   // 64
    const float* f = feat + b * 1024;
    const float* w = wl + j * 1024;
    float s = 0.f;
    for (int k = lane; k < 1024; k += 64) s = fmaf(f[k], w[k], s);
#pragma unroll
    for (int off = 32; off > 0; off >>= 1) s += __shfl_down(s, off);
    if (lane == 0) out[b * 2304 + 2048 + j] = s + bl[j];
}

extern "C" void kernel_launch(void* const* d_in, const int* in_sizes, int n_in,
                              void* d_out, int out_size, void* d_ws, size_t ws_size,
                              hipStream_t stream) {
    const float* x  = (const float*)d_in[0];
    const float* x1 = (const float*)d_in[1];
    const float* w1 = (const float*)d_in[2];
    const float* g1 = (const float*)d_in[3];
    const float* b1 = (const float*)d_in[4];
    const float* m1 = (const float*)d_in[5];
    const float* v1 = (const float*)d_in[6];
    const float* w2 = (const float*)d_in[7];
    const float* g2 = (const float*)d_in[8];
    const float* b2 = (const float*)d_in[9];
    const float* m2 = (const float*)d_in[10];
    const float* v2 = (const float*)d_in[11];
    const float* wl = (const float*)d_in[12];
    const float* bl = (const float*)d_in[13];
    float* out = (float*)d_out;

    float* wsf = (float*)d_ws;
    unsigned* cnt2 = (unsigned*)(wsf + OFF_CNT2);
    unsigned* cnt1 = (unsigned*)(wsf + OFF_CNT1);
    float* hab  = wsf + OFF_HAB;
    float* hl   = wsf + OFF_HL;
    float* feat = wsf + OFF_FEAT;
    __hip_bfloat16* w2r = (__hip_bfloat16*)(wsf + OFF_W2R);
    __hip_bfloat16* zt  = (__hip_bfloat16*)(wsf + OFF_ZT);

    init_zero<<<(ZT_WORDS + 255) / 256, 256, 0, stream>>>(cnt2, cnt1, feat, (unsigned*)zt);
    hist_kernel<<<dim3(64, 16), 256, 0, stream>>>(x1, cnt2, cnt1);
    hist_norm<<<16, 256, 0, stream>>>(cnt2, cnt1, hab, hl);
    conv1_pool<<<dim3(33, 16), 256, 0, stream>>>(hab, hl, w1, g1, b1, m1, v1, zt);
    w2_prep<<<(9 * 1024 * 128 + 255) / 256, 256, 0, stream>>>(w2, w2r);
    conv2_mfma<<<dim3(8, 9, 16), 256, 0, stream>>>(zt, w2r, g2, b2, m2, v2, feat);
    copy_x<<<(16 * 2048 + 255) / 256, 256, 0, stream>>>(x, out);
    linear_head<<<dim3(256, 16), 64, 0, stream>>>(feat, wl, bl, out);
}

// Round 5
// 103.896 us; speedup vs baseline: 6.2700x; 1.3140x over previous
//
#include <hip/hip_runtime.h>
#include <hip/hip_bf16.h>
#include <math.h>

typedef __attribute__((ext_vector_type(8))) short bf16x8;
typedef __attribute__((ext_vector_type(4))) float f32x4;

#define HW 262144        // 512*512
#define M_SP 1089        // 33*33

// ---- ws layout in 4-byte words ----
#define OFF_CNT2 0                        // 16*4096 u32
#define OFF_CNT1 (OFF_CNT2 + 16*4096)     // 512
#define OFF_HAB  (OFF_CNT1 + 512)         // 16*4096 f32
#define OFF_HL   (OFF_HAB + 16*4096)      // 512
#define OFF_FEAT (OFF_HL + 512)           // 16*1024 f32
#define OFF_W2R  (OFF_FEAT + 16*1024)     // bf16[9][1024][128] = 589824 words
#define OFF_ZT   (OFF_W2R + 589824)       // bf16[16][37][35][128] = 1326080 words
#define ZT_WORDS 1326080

// ---------------- init ----------------
__global__ void init_zero(unsigned* cnt2, unsigned* cnt1, float* feat, unsigned* ztw) {
    int i = blockIdx.x * 256 + threadIdx.x;
    if (i < ZT_WORDS) ztw[i] = 0u;
    if (i < 16 * 4096) cnt2[i] = 0u;
    if (i < 512) cnt1[i] = 0u;
    if (i < 16 * 1024) feat[i] = 0.f;
}

// ---------------- histograms ----------------
__device__ inline unsigned wred_u32(unsigned v) {
#pragma unroll
    for (int off = 32; off > 0; off >>= 1) v += __shfl_down(v, off);
    return v;
}

__global__ __launch_bounds__(256) void hist_kernel(const float* __restrict__ x1,
                                                   unsigned* __restrict__ cnt2,
                                                   unsigned* __restrict__ cnt1) {
    int b = blockIdx.y;
    __shared__ unsigned h2[4096];
    for (int i = threadIdx.x; i < 4096; i += 256) h2[i] = 0u;
    __syncthreads();

    const float4* L4 = (const float4*)(x1 + (size_t)b * 3 * HW);
    const float4* A4 = (const float4*)(x1 + (size_t)b * 3 * HW + HW);
    const float4* B4 = (const float4*)(x1 + (size_t)b * 3 * HW + 2 * HW);
    const int start = blockIdx.x * 4096;   // float4 units; 4096 per block (grid.x=16)

    unsigned c0=0,c1=0,c2=0,c3=0,c4=0,c5=0,c6=0,c7=0;
#pragma unroll 1
    for (int it = 0; it < 16; it += 4) {
        float4 lb[4], ab[4], bbv[4];
#pragma unroll
        for (int u = 0; u < 4; ++u) {
            int idx = start + (it + u) * 256 + threadIdx.x;
            lb[u] = L4[idx]; ab[u] = A4[idx]; bbv[u] = B4[idx];
        }
#pragma unroll
        for (int u = 0; u < 4; ++u) {
            const float lv[4] = {lb[u].x, lb[u].y, lb[u].z, lb[u].w};
            const float av[4] = {ab[u].x, ab[u].y, ab[u].z, ab[u].w};
            const float bv[4] = {bbv[u].x, bbv[u].y, bbv[u].z, bbv[u].w};
#pragma unroll
            for (int e = 0; e < 4; ++e) {
                float l = lv[e], a = av[e], bb = bv[e];
                float va = (a + 1.f) * 0.5f;
                float vb = (bb + 1.f) * 0.5f;
                if (a != 0.f && bb != 0.f && va >= 0.f && va <= 1.f && vb >= 0.f && vb <= 1.f) {
                    int ia = min(max((int)floorf(va * 64.f), 0), 63);
                    int ib = min(max((int)floorf(vb * 64.f), 0), 63);
                    atomicAdd(&h2[ia * 64 + ib], 1u);
                }
                float vl = (l + 1.f) * 0.5f;
                if (l != 0.f && vl >= 0.f && vl <= 1.f) {
                    int il = min(max((int)floorf(vl * 8.f), 0), 7);
                    c0 += (il == 0); c1 += (il == 1); c2 += (il == 2); c3 += (il == 3);
                    c4 += (il == 4); c5 += (il == 5); c6 += (il == 6); c7 += (il == 7);
                }
            }
        }
    }
    c0 = wred_u32(c0); c1 = wred_u32(c1); c2 = wred_u32(c2); c3 = wred_u32(c3);
    c4 = wred_u32(c4); c5 = wred_u32(c5); c6 = wred_u32(c6); c7 = wred_u32(c7);
    if ((threadIdx.x & 63) == 0) {
        if (c0) atomicAdd(&cnt1[b * 8 + 0], c0);
        if (c1) atomicAdd(&cnt1[b * 8 + 1], c1);
        if (c2) atomicAdd(&cnt1[b * 8 + 2], c2);
        if (c3) atomicAdd(&cnt1[b * 8 + 3], c3);
        if (c4) atomicAdd(&cnt1[b * 8 + 4], c4);
        if (c5) atomicAdd(&cnt1[b * 8 + 5], c5);
        if (c6) atomicAdd(&cnt1[b * 8 + 6], c6);
        if (c7) atomicAdd(&cnt1[b * 8 + 7], c7);
    }
    __syncthreads();
    for (int i = threadIdx.x; i < 4096; i += 256)
        if (h2[i]) atomicAdd(&cnt2[b * 4096 + i], h2[i]);
}

__global__ __launch_bounds__(256) void hist_norm(const unsigned* __restrict__ cnt2,
                                                 const unsigned* __restrict__ cnt1,
                                                 float* __restrict__ hab,
                                                 float* __restrict__ hl) {
    int b = blockIdx.x;
    __shared__ float red[256];
    unsigned s = 0;
    for (int i = threadIdx.x; i < 4096; i += 256) s += cnt2[b * 4096 + i];
    red[threadIdx.x] = (float)s;
    __syncthreads();
    for (int off = 128; off > 0; off >>= 1) {
        if (threadIdx.x < off) red[threadIdx.x] += red[threadIdx.x + off];
        __syncthreads();
    }
    float inv2 = 1.f / red[0];
    for (int i = threadIdx.x; i < 4096; i += 256) {
        int r = i >> 6, c = i & 63;
        hab[b * 4096 + i] = (float)cnt2[b * 4096 + c * 64 + r] * inv2;
    }
    if (threadIdx.x < 8) {
        unsigned t = 0;
        for (int k = 0; k < 8; ++k) t += cnt1[b * 8 + k];
        hl[b * 8 + threadIdx.x] = (float)cnt1[b * 8 + threadIdx.x] / (float)t;
    }
}

// ---------------- w2 [1024][128][3][3] -> w2r[tap][oc][ic] bf16 ----------------
__global__ void w2_prep(const float* __restrict__ w2, __hip_bfloat16* __restrict__ w2r) {
    int i = blockIdx.x * 256 + threadIdx.x;
    if (i < 9 * 1024 * 128) {
        int tap = i >> 17;
        int rem = i & 131071;
        int oc = rem >> 7, ic = rem & 127;
        w2r[i] = __float2bfloat16(w2[oc * 1152 + ic * 9 + tap]);
    }
}

// ---------------- conv1 + BN + maxpool + relu -> zt[b][37][35][128] bf16 (halo zeroed) --------
__global__ __launch_bounds__(256) void conv1_pool(
    const float* __restrict__ hab, const float* __restrict__ hl,
    const float* __restrict__ w1, const float* __restrict__ g1,
    const float* __restrict__ b1v, const float* __restrict__ m1,
    const float* __restrict__ v1, __hip_bfloat16* __restrict__ zt)
{
    const int p = blockIdx.x;   // 0..32
    const int b = blockIdx.y;
    __shared__ float aL[128], cL[128], sL[128];
    __shared__ float Hrow[3][64];
    __shared__ float qmx[33], qmn[33];
    __shared__ int qbd[33];
    const int tid = threadIdx.x;
    if (tid < 128) {
        int oc = tid;
        float inv = g1[oc] * rsqrtf(v1[oc] + 1e-5f);
        float s = b1v[oc] - m1[oc] * inv;
        float Kc = 0.f;
#pragma unroll
        for (int c = 1; c < 9; ++c) Kc = fmaf(w1[oc * 9 + c], hl[b * 8 + c - 1], Kc);
        aL[oc] = w1[oc * 9] * inv;
        cL[oc] = fmaf(Kc, inv, s);
        sL[oc] = s;
    }
    if (tid < 192) {
        int rr = tid >> 6, cc = tid & 63;
        int row = 2 * p - 2 + rr;
        Hrow[rr][cc] = (row >= 0 && row < 64) ? hab[b * 4096 + row * 64 + cc] : 0.f;
    }
    __syncthreads();
    if (tid < 33) {
        int q = tid;
        float mx = -1e30f, mn = 1e30f;
        int bd = 0;
#pragma unroll
        for (int dy = 0; dy < 3; ++dy) {
            int yi = 2 * p - 1 + dy;
            if (yi < 0 || yi > 65) continue;
#pragma unroll
            for (int dx = 0; dx < 3; ++dx) {
                int yj = 2 * q - 1 + dx;
                if (yj < 0 || yj > 65) continue;
                if (yi == 0 || yi == 65 || yj == 0 || yj == 65) bd = 1;
                else {
                    float h = Hrow[dy][2 * q - 2 + dx];
                    mx = fmaxf(mx, h); mn = fminf(mn, h);
                }
            }
        }
        qmx[q] = mx; qmn[q] = mn; qbd[q] = bd;
    }
    __syncthreads();
    __hip_bfloat16* zrow = zt + (((size_t)b * 37 + (p + 1)) * 35 + 1) * 128;
    for (int it = tid; it < 33 * 128; it += 256) {
        int q = it >> 7, oc = it & 127;
        float a = aL[oc];
        float v = fmaf(a, (a > 0.f ? qmx[q] : qmn[q]), cL[oc]);
        if (qbd[q]) v = fmaxf(v, sL[oc]);
        v = fmaxf(v, 0.f);
        zrow[q * 128 + oc] = __float2bfloat16(v);
    }
}

// ---------------- conv2 as 9 tap-GEMMs, bf16 MFMA, fused BN+ReLU+mean ----------------
__global__ __launch_bounds__(256, 2) void conv2_mfma(
        const __hip_bfloat16* __restrict__ zt,
        const __hip_bfloat16* __restrict__ w2r,
        const float* __restrict__ g2, const float* __restrict__ b2v,
        const float* __restrict__ m2, const float* __restrict__ v2,
        float* __restrict__ feat)
{
    __shared__ char lds[65536];   // 2 buffers x (A 16KB + B 16KB)
    const int tid = threadIdx.x;
    const int lane = tid & 63, wid = tid >> 6;
    const int b = blockIdx.z;
    const int nbase = blockIdx.x * 128;
    const int mbase = blockIdx.y * 128;
    const int lr16 = lane & 15, lk = lane >> 4;
    const int wm = (wid >> 1) * 64, wn = (wid & 1) * 64;

    const int slot = lane & 7, rr8 = lane >> 3;
    const char* aS[4];
    const char* bS[4];
    {
        const char* ztb = (const char*)zt + (size_t)b * (37 * 35 * 128 * 2);
#pragma unroll
        for (int v = 0; v < 4; ++v) {
            int r = wid * 32 + v * 8 + rr8;
            int sl = (slot ^ (r & 7)) << 4;
            int m = mbase + r;
            int p = m / 33, q = m - p * 33;
            aS[v] = ztb + (p * 35 + q) * 256 + sl;
            bS[v] = (const char*)w2r + (size_t)(nbase + r) * 256 + sl;
        }
    }

    f32x4 acc[4][4];
#pragma unroll
    for (int i = 0; i < 4; ++i)
#pragma unroll
        for (int j = 0; j < 4; ++j) acc[i][j] = (f32x4){0.f, 0.f, 0.f, 0.f};

    auto stage = [&](int d, int s) {
        const int tap = s >> 1, kby = (s & 1) << 7;
        const int kh = tap / 3, kw = tap - kh * 3;
        const int aoff = (kh * 35 + kw) * 256 + kby;
        const int boff = tap * 262144 + kby;
        char* ab = lds + d * 32768 + wid * 4096;
        char* bb = ab + 16384;
#pragma unroll
        for (int v = 0; v < 4; ++v)
            __builtin_amdgcn_global_load_lds(
                (const __attribute__((address_space(1))) unsigned int*)(aS[v] + aoff),
                (__attribute__((address_space(3))) unsigned int*)(ab + v * 1024), 16, 0, 0);
#pragma unroll
        for (int v = 0; v < 4; ++v)
            __builtin_amdgcn_global_load_lds(
                (const __attribute__((address_space(1))) unsigned int*)(bS[v] + boff),
                (__attribute__((address_space(3))) unsigned int*)(bb + v * 1024), 16, 0, 0);
    };

    auto compute = [&](int d) {
        const char* Ab = lds + d * 32768;
        const char* Bb = Ab + 16384;
#pragma unroll
        for (int ks = 0; ks < 2; ++ks) {
            bf16x8 af[4], bfr[4];
#pragma unroll
            for (int i = 0; i < 4; ++i) {
                int row = wm + i * 16 + lr16;
                af[i] = *(const bf16x8*)(Ab + row * 128 + (((ks * 4 + lk) ^ (row & 7)) << 4));
            }
#pragma unroll
            for (int j = 0; j < 4; ++j) {
                int row = wn + j * 16 + lr16;
                bfr[j] = *(const bf16x8*)(Bb + row * 128 + (((ks * 4 + lk) ^ (row & 7)) << 4));
            }
#pragma unroll
            for (int i = 0; i < 4; ++i)
#pragma unroll
                for (int j = 0; j < 4; ++j)
                    acc[i][j] = __builtin_amdgcn_mfma_f32_16x16x32_bf16(af[i], bfr[j], acc[i][j], 0, 0, 0);
        }
    };

    stage(0, 0);
    __syncthreads();
#pragma unroll 1
    for (int s = 0; s < 18; ++s) {
        if (s < 17) stage((s + 1) & 1, s + 1);
        compute(s & 1);
        __syncthreads();
    }

    float* red = (float*)lds;
#pragma unroll
    for (int j = 0; j < 4; ++j) {
        int nl = wn + j * 16 + lr16;
        int n = nbase + nl;
        float inv = g2[n] * rsqrtf(v2[n] + 1e-5f);
        float sh = b2v[n] - m2[n] * inv;
        float ssum = 0.f;
#pragma unroll
        for (int i = 0; i < 4; ++i) {
            int mlb = wm + i * 16 + lk * 4;
#pragma unroll
            for (int r = 0; r < 4; ++r) {
                if (mbase + mlb + r < M_SP)
                    ssum += fmaxf(fmaf(acc[i][j][r], inv, sh), 0.f);
            }
        }
        red[((wid >> 1) * 4 + lk) * 128 + nl] = ssum;
    }
    __syncthreads();
    if (tid < 128) {
        float s = 0.f;
#pragma unroll
        for (int c = 0; c < 8; ++c) s += red[c * 128 + tid];
        atomicAdd(&feat[b * 1024 + nbase + tid], s * (1.f / 1089.f));
    }
}

// ---------------- head ----------------
__global__ void copy_x(const float* __restrict__ x, float* __restrict__ out) {
    int i = blockIdx.x * 256 + threadIdx.x;
    if (i < 16 * 2048) {
        int b = i >> 11, j = i & 2047;
        out[b * 2304 + j] = x[i];
    }
}

__global__ void linear_head(const float* __restrict__ feat, const float* __restrict__ wl,
                            const float* __restrict__ bl, float* __restrict__ out) {
    int j = blockIdx.x, b = blockIdx.y;
    int lane = threadIdx.x;   // 64
    const float* f = feat + b * 1024;
    const float* w = wl + j * 1024;
    float s = 0.f;
    for (int k = lane; k < 1024; k += 64) s = fmaf(f[k], w[k], s);
#pragma unroll
    for (int off = 32; off > 0; off >>= 1) s += __shfl_down(s, off);
    if (lane == 0) out[b * 2304 + 2048 + j] = s + bl[j];
}

extern "C" void kernel_launch(void* const* d_in, const int* in_sizes, int n_in,
                              void* d_out, int out_size, void* d_ws, size_t ws_size,
                              hipStream_t stream) {
    const float* x  = (const float*)d_in[0];
    const float* x1 = (const float*)d_in[1];
    const float* w1 = (const float*)d_in[2];
    const float* g1 = (const float*)d_in[3];
    const float* b1 = (const float*)d_in[4];
    const float* m1 = (const float*)d_in[5];
    const float* v1 = (const float*)d_in[6];
    const float* w2 = (const float*)d_in[7];
    const float* g2 = (const float*)d_in[8];
    const float* b2 = (const float*)d_in[9];
    const float* m2 = (const float*)d_in[10];
    const float* v2 = (const float*)d_in[11];
    const float* wl = (const float*)d_in[12];
    const float* bl = (const float*)d_in[13];
    float* out = (float*)d_out;

    float* wsf = (float*)d_ws;
    unsigned* cnt2 = (unsigned*)(wsf + OFF_CNT2);
    unsigned* cnt1 = (unsigned*)(wsf + OFF_CNT1);
    float* hab  = wsf + OFF_HAB;
    float* hl   = wsf + OFF_HL;
    float* feat = wsf + OFF_FEAT;
    __hip_bfloat16* w2r = (__hip_bfloat16*)(wsf + OFF_W2R);
    __hip_bfloat16* zt  = (__hip_bfloat16*)(wsf + OFF_ZT);

    init_zero<<<(ZT_WORDS + 255) / 256, 256, 0, stream>>>(cnt2, cnt1, feat, (unsigned*)zt);
    hist_kernel<<<dim3(16, 16), 256, 0, stream>>>(x1, cnt2, cnt1);
    hist_norm<<<16, 256, 0, stream>>>(cnt2, cnt1, hab, hl);
    conv1_pool<<<dim3(33, 16), 256, 0, stream>>>(hab, hl, w1, g1, b1, m1, v1, zt);
    w2_prep<<<(9 * 1024 * 128 + 255) / 256, 256, 0, stream>>>(w2, w2r);
    conv2_mfma<<<dim3(8, 9, 16), 256, 0, stream>>>(zt, w2r, g2, b2, m2, v2, feat);
    copy_x<<<(16 * 2048 + 255) / 256, 256, 0, stream>>>(x, out);
    linear_head<<<dim3(256, 16), 64, 0, stream>>>(feat, wl, bl, out);
}